// Round 5
// baseline (430.644 us; speedup 1.0000x reference)
//
#include <hip/hip_runtime.h>

#define NN 512
#define MM 512
#define NEO 510
#define PLANE (NN * MM)          // 262144
#define STATE_CH 26
#define OUT_DIM 28
#define FEAT 245
#define THRESH 0.0007f

// ---- W12 = W1 @ W2 (245x28), b12 = b1 @ W2 + b2 (28) ----
__global__ void prep_w12(const float* __restrict__ W1, const float* __restrict__ b1,
                         const float* __restrict__ W2, const float* __restrict__ b2,
                         float* __restrict__ W12, float* __restrict__ b12) {
  int t = blockIdx.x * 256 + threadIdx.x;
  if (t < FEAT * OUT_DIM) {
    int f = t / OUT_DIM, k = t - f * OUT_DIM;
    float s = 0.0f;
    for (int jj = 0; jj < FEAT; ++jj) s = fmaf(W1[f * FEAT + jj], W2[jj * OUT_DIM + k], s);
    W12[t] = s;
  } else if (t < FEAT * OUT_DIM + OUT_DIM) {
    int k = t - FEAT * OUT_DIM;
    float s = b2[k];
    for (int jj = 0; jj < FEAT; ++jj) s = fmaf(b1[jj], W2[jj * OUT_DIM + k], s);
    b12[k] = s;
  }
}

// ---- state0 [512][512][26] -> planar [26][512][512], into BOTH buffers ----
__global__ void transpose_state(const float* __restrict__ s0,
                                float* __restrict__ A, float* __restrict__ B) {
  int idx = blockIdx.x * 256 + threadIdx.x;   // 0..PLANE-1
  const float* src = s0 + (size_t)idx * STATE_CH;
#pragma unroll
  for (int c = 0; c < STATE_CH; ++c) {
    float v = src[c];
    A[c * PLANE + idx] = v;
    B[c * PLANE + idx] = v;
  }
}

template <bool LAST>
__global__ __launch_bounds__(256) void nca_step(
    const float* __restrict__ img, const float* __restrict__ sold, float* __restrict__ snew,
    const int* __restrict__ pold, int* __restrict__ pnew,
    const float* __restrict__ W12, const float* __restrict__ b12,
    float* __restrict__ out0, float* __restrict__ out1) {
  const int j = blockIdx.x * 64 + (int)(threadIdx.x & 63);
  const int i = blockIdx.y * 4 + (int)(threadIdx.x >> 6);
  if (i >= NEO || j >= NEO) return;
  const int cell = i * NEO + j;
  const int2 p = ((const int2*)pold)[cell];

  float acc[OUT_DIM];
#pragma unroll
  for (int k = 0; k < OUT_DIM; ++k) acc[k] = b12[k];

  const float* w = W12;
#pragma unroll 1
  for (int di = 0; di < 3; ++di) {
#pragma unroll 1
    for (int dj = 0; dj < 3; ++dj) {
      float vals[27];
      vals[0] = img[(p.x + di) * MM + (p.y + dj)];
      const int base = (i + di) * MM + (j + dj);
#pragma unroll
      for (int c = 0; c < STATE_CH; ++c) vals[1 + c] = sold[c * PLANE + base];
#pragma unroll
      for (int t = 0; t < 27; ++t) {
#pragma unroll
        for (int k = 0; k < OUT_DIM; ++k)
          acc[k] = fmaf(vals[t], w[t * OUT_DIM + k], acc[k]);
      }
      w += 27 * OUT_DIM;
    }
  }
  const float posx = (float)(p.x - 256) * (1.0f / 256.0f);
  const float posy = (float)(p.y - 256) * (1.0f / 256.0f);
#pragma unroll
  for (int k = 0; k < OUT_DIM; ++k) acc[k] = fmaf(posx, w[k], acc[k]);
#pragma unroll
  for (int k = 0; k < OUT_DIM; ++k) acc[k] = fmaf(posy, w[OUT_DIM + k], acc[k]);

  const int nb = (i + 1) * MM + (j + 1);
  if (!LAST) {
    const float ax = acc[26], ay = acc[27];
    int dx = (ax < -THRESH) ? -1 : ((ax > THRESH) ? 1 : 0);
    int dy = (ay < -THRESH) ? -1 : ((ay > THRESH) ? 1 : 0);
    int nx = min(max(p.x + dx, 0), NEO - 1);
    int ny = min(max(p.y + dy, 0), NEO - 1);
    ((int2*)pnew)[cell] = make_int2(nx, ny);
#pragma unroll
    for (int c = 0; c < STATE_CH; ++c)
      snew[c * PLANE + nb] = sold[c * PLANE + nb] + acc[c];
  } else {
    // out0: final state slice channels 16..25, layout [i][j][c10]
    float2* o0 = (float2*)(out0 + (size_t)cell * 10);
#pragma unroll
    for (int c = 0; c < 5; ++c) {
      float2 v;
      v.x = sold[(16 + 2 * c) * PLANE + nb] + acc[16 + 2 * c];
      v.y = sold[(17 + 2 * c) * PLANE + nb] + acc[17 + 2 * c];
      o0[c] = v;
    }
    // out1: final guesses, layout [cell][28]
    float4* o1 = (float4*)(out1 + (size_t)cell * OUT_DIM);
#pragma unroll
    for (int q = 0; q < 7; ++q)
      o1[q] = make_float4(acc[4 * q], acc[4 * q + 1], acc[4 * q + 2], acc[4 * q + 3]);
  }
}

extern "C" void kernel_launch(void* const* d_in, const int* in_sizes, int n_in,
                              void* d_out, int out_size, void* d_ws, size_t ws_size,
                              hipStream_t stream) {
  const float* img    = (const float*)d_in[0];
  const float* state0 = (const float*)d_in[1];
  const int*   perc0  = (const int*)d_in[2];
  const float* W1     = (const float*)d_in[3];
  const float* b1     = (const float*)d_in[4];
  const float* W2     = (const float*)d_in[5];
  const float* b2     = (const float*)d_in[6];
  float* out = (float*)d_out;

  float* stateA = (float*)d_ws;                          // 26*PLANE f32
  float* stateB = stateA + (size_t)STATE_CH * PLANE;     // 26*PLANE f32
  int*   percA  = (int*)(stateB + (size_t)STATE_CH * PLANE); // 510*510*2 i32
  int*   percB  = percA + (size_t)NEO * NEO * 2;
  float* W12    = (float*)(percB + (size_t)NEO * NEO * 2);   // 6860 f32
  float* b12    = W12 + FEAT * OUT_DIM;

  float* out0 = out;                       // 510*510*10
  float* out1 = out + (size_t)NEO * NEO * 10;  // 510*510*28

  prep_w12<<<dim3(27), dim3(256), 0, stream>>>(W1, b1, W2, b2, W12, b12);
  transpose_state<<<dim3(PLANE / 256), dim3(256), 0, stream>>>(state0, stateA, stateB);

  dim3 grid(8, 128), block(256);
  nca_step<false><<<grid, block, 0, stream>>>(img, stateA, stateB, perc0, percB, W12, b12, nullptr, nullptr);
  nca_step<false><<<grid, block, 0, stream>>>(img, stateB, stateA, percB, percA, W12, b12, nullptr, nullptr);
  nca_step<false><<<grid, block, 0, stream>>>(img, stateA, stateB, percA, percB, W12, b12, nullptr, nullptr);
  nca_step<true ><<<grid, block, 0, stream>>>(img, stateB, nullptr, percB, nullptr, W12, b12, out0, out1);
}